// Round 1
// baseline (76.976 us; speedup 1.0000x reference)
//
#include <hip/hip_runtime.h>

#define BATCH 262144

struct cplx { float re, im; };

// General rotation: vi' = ep*ct*vi - st*vj ; vj' = ep*st*vi + ct*vj, ep=(pr,pi)
__device__ __forceinline__ void rot(cplx& vi, cplx& vj, float ct, float st,
                                    float pr, float pi) {
    float ar = pr * ct, ai = pi * ct;   // ep*ct
    float br = pr * st, bi = pi * st;   // ep*st
    cplx ni, nj;
    ni.re = ar * vi.re - ai * vi.im - st * vj.re;
    ni.im = ar * vi.im + ai * vi.re - st * vj.im;
    nj.re = br * vi.re - bi * vi.im + ct * vj.re;
    nj.im = br * vi.im + bi * vi.re + ct * vj.im;
    vi = ni; vj = nj;
}

// phi == 0 specialization (ep = 1): pure real Givens rotation
__device__ __forceinline__ void rot0(cplx& vi, cplx& vj, float ct, float st) {
    cplx ni, nj;
    ni.re = ct * vi.re - st * vj.re;
    ni.im = ct * vi.im - st * vj.im;
    nj.re = st * vi.re + ct * vj.re;
    nj.im = st * vi.im + ct * vj.im;
    vi = ni; vj = nj;
}

__global__ __launch_bounds__(256) void bqnn_kernel(
    const float* __restrict__ x,
    const float* __restrict__ pphi,
    const float* __restrict__ pth,
    const float* __restrict__ ink,
    const float* __restrict__ inb,
    float* __restrict__ out) {
    const int tid = blockIdx.x * 256 + threadIdx.x;

    // Load this element's 12 inputs as 3x float4 (48 B/thread, lines fully used)
    const float4* x4 = reinterpret_cast<const float4*>(x) + tid * 3;
    float4 v0 = x4[0], v1 = x4[1], v2 = x4[2];
    float xs[12] = { v0.x, v0.y, v0.z, v0.w,
                     v1.x, v1.y, v1.z, v1.w,
                     v2.x, v2.y, v2.z, v2.w };
    #pragma unroll
    for (int m = 0; m < 12; ++m) xs[m] = xs[m] * ink[m] + inb[m];

    // theta / phi schedule (uniform params + per-element xs)
    float th[14], ph[14];
    th[0] = pth[0]; th[1] = pth[1]; th[2] = pth[2]; th[3] = pth[3];
    th[4] = xs[3];  th[5] = xs[4];  th[6] = xs[5];
    th[7] = pth[4]; th[8] = pth[5];
    th[9] = xs[9];  th[10] = xs[10]; th[11] = xs[11];
    th[12] = pth[6]; th[13] = pth[7];
    ph[0] = ph[1] = ph[2] = ph[3] = 0.f;
    ph[4] = xs[0];  ph[5] = xs[1];  ph[6] = xs[2];
    ph[7] = pphi[0]; ph[8] = pphi[1];
    ph[9] = xs[6];  ph[10] = xs[7]; ph[11] = xs[8];
    ph[12] = pphi[2]; ph[13] = pphi[3];

    const int MI[14] = {0, 4, 1, 3,  0, 2, 4, 1, 3,  0, 2, 4, 1, 3};
    const int MJ[14] = {1, 5, 2, 4,  1, 3, 5, 2, 4,  1, 3, 5, 2, 4};

    // Only columns 0 and 3 of U are ever read -> track two complex 6-vectors.
    cplx a[6], b[6];
    #pragma unroll
    for (int m = 0; m < 6; ++m) { a[m] = {0.f, 0.f}; b[m] = {0.f, 0.f}; }
    a[0].re = 1.f;  // column 0 of I
    b[3].re = 1.f;  // column 3 of I

    #pragma unroll
    for (int k = 0; k < 14; ++k) {
        float st, ct;
        __sincosf(th[k], &st, &ct);
        const int i = MI[k], j = MJ[k];
        if (k < 4) {
            rot0(a[i], a[j], ct, st);
            rot0(b[i], b[j], ct, st);
        } else {
            float sp, cp;
            __sincosf(ph[k], &sp, &cp);
            rot(a[i], a[j], ct, st, cp, sp);
            rot(b[i], b[j], ct, st, cp, sp);
        }
    }

    // 15 output pairs: amp = a[i]*b[j] + a[j]*b[i]; out = |amp| / max(norm, eps)
    float mag2[15];
    float s = 0.f;
    int idx = 0;
    #pragma unroll
    for (int i = 0; i < 6; ++i) {
        #pragma unroll
        for (int j = i + 1; j < 6; ++j) {
            float re = a[i].re * b[j].re - a[i].im * b[j].im
                     + a[j].re * b[i].re - a[j].im * b[i].im;
            float im = a[i].re * b[j].im + a[i].im * b[j].re
                     + a[j].re * b[i].im + a[j].im * b[i].re;
            float m2 = re * re + im * im;
            s += m2;
            mag2[idx++] = m2;
        }
    }
    float norm = __fsqrt_rn(s);
    float inv = 1.f / fmaxf(norm, 1e-12f);

    float* o = out + (long long)tid * 15;
    #pragma unroll
    for (int k = 0; k < 15; ++k) o[k] = __fsqrt_rn(mag2[k]) * inv;
}

extern "C" void kernel_launch(void* const* d_in, const int* in_sizes, int n_in,
                              void* d_out, int out_size, void* d_ws, size_t ws_size,
                              hipStream_t stream) {
    const float* x    = (const float*)d_in[0];
    const float* pphi = (const float*)d_in[1];
    const float* pth  = (const float*)d_in[2];
    const float* ink  = (const float*)d_in[3];
    const float* inb  = (const float*)d_in[4];
    float* out = (float*)d_out;

    bqnn_kernel<<<BATCH / 256, 256, 0, stream>>>(x, pphi, pth, ink, inb, out);
}

// Round 2
// 75.187 us; speedup vs baseline: 1.0238x; 1.0238x over previous
//
#include <hip/hip_runtime.h>

#define BATCH 262144

struct C { float r, i; };

// General rotation on one column entry pair: u' = ep*ct*u - st*v ; v' = ep*st*u + ct*v
__device__ __forceinline__ void rotp(C& u, C& v, float ct, float st, float cp, float sp) {
    float ar = cp * ct, ai = sp * ct;   // ep*ct
    float br = cp * st, bi = sp * st;   // ep*st
    C nu, nv;
    nu.r = ar * u.r - ai * u.i - st * v.r;
    nu.i = ar * u.i + ai * u.r - st * v.i;
    nv.r = br * u.r - bi * u.i + ct * v.r;
    nv.i = br * u.i + bi * u.r + ct * v.i;
    u = nu; v = nv;
}

// phi == 0: pure real Givens rotation
__device__ __forceinline__ void rotr(C& u, C& v, float ct, float st) {
    C nu, nv;
    nu.r = ct * u.r - st * v.r;
    nu.i = ct * u.i - st * v.i;
    nv.r = st * u.r + ct * v.r;
    nv.i = st * u.i + ct * v.i;
    u = nu; v = nv;
}

__global__ __launch_bounds__(256) void bqnn_kernel(
    const float* __restrict__ x,
    const float* __restrict__ pphi,
    const float* __restrict__ pth,
    const float* __restrict__ ink,
    const float* __restrict__ inb,
    float* __restrict__ out) {
    __shared__ float ls[256 * 15];

    const int t = threadIdx.x;
    const int elem = blockIdx.x * 256 + t;

    // 12 inputs as 3x float4 (48 B/thread; every 128B line fully consumed)
    const float4* x4 = reinterpret_cast<const float4*>(x) + (long long)elem * 3;
    float4 v0 = x4[0], v1 = x4[1], v2 = x4[2];

    // xs[m] = x*k + b, fully scalarized (constant indices only)
    const float xs0  = v0.x * ink[0]  + inb[0];
    const float xs1  = v0.y * ink[1]  + inb[1];
    const float xs2  = v0.z * ink[2]  + inb[2];
    const float xs3  = v0.w * ink[3]  + inb[3];
    const float xs4  = v1.x * ink[4]  + inb[4];
    const float xs5  = v1.y * ink[5]  + inb[5];
    const float xs6  = v1.z * ink[6]  + inb[6];
    const float xs7  = v1.w * ink[7]  + inb[7];
    const float xs8  = v2.x * ink[8]  + inb[8];
    const float xs9  = v2.y * ink[9]  + inb[9];
    const float xs10 = v2.z * ink[10] + inb[10];
    const float xs11 = v2.w * ink[11] + inb[11];

    // Only columns 0 and 3 of U are read downstream: track two complex 6-vectors
    // in named registers (no arrays -> no scratch risk).
    C a0{1.f,0.f}, a1{0.f,0.f}, a2{0.f,0.f}, a3{0.f,0.f}, a4{0.f,0.f}, a5{0.f,0.f};
    C b0{0.f,0.f}, b1{0.f,0.f}, b2{0.f,0.f}, b3{1.f,0.f}, b4{0.f,0.f}, b5{0.f,0.f};

#define ROTR(I, J, TH) do { \
        float st_ = __sinf(TH), ct_ = __cosf(TH); \
        rotr(a##I, a##J, ct_, st_); \
        rotr(b##I, b##J, ct_, st_); \
    } while (0)

#define ROTP(I, J, TH, PH) do { \
        float st_ = __sinf(TH), ct_ = __cosf(TH); \
        float sp_ = __sinf(PH), cp_ = __cosf(PH); \
        rotp(a##I, a##J, ct_, st_, cp_, sp_); \
        rotp(b##I, b##J, ct_, st_, cp_, sp_); \
    } while (0)

    // Rotation schedule (MODES x {theta, phi}):
    ROTR(0, 1, pth[0]);            // k=0
    ROTR(4, 5, pth[1]);            // k=1
    ROTR(1, 2, pth[2]);            // k=2
    ROTR(3, 4, pth[3]);            // k=3
    ROTP(0, 1, xs3,  xs0);         // k=4
    ROTP(2, 3, xs4,  xs1);         // k=5
    ROTP(4, 5, xs5,  xs2);         // k=6
    ROTP(1, 2, pth[4], pphi[0]);   // k=7
    ROTP(3, 4, pth[5], pphi[1]);   // k=8
    ROTP(0, 1, xs9,  xs6);         // k=9
    ROTP(2, 3, xs10, xs7);         // k=10
    ROTP(4, 5, xs11, xs8);         // k=11
    ROTP(1, 2, pth[6], pphi[2]);   // k=12
    ROTP(3, 4, pth[7], pphi[3]);   // k=13

#undef ROTR
#undef ROTP

    // amp_ij = a_i*b_j + a_j*b_i for the 15 pairs; |amp|/max(norm,eps)
#define PAIR(I, J, K) \
    { float re_ = a##I.r * b##J.r - a##I.i * b##J.i + a##J.r * b##I.r - a##J.i * b##I.i; \
      float im_ = a##I.r * b##J.i + a##I.i * b##J.r + a##J.r * b##I.i + a##J.i * b##I.r; \
      m##K = re_ * re_ + im_ * im_; s += m##K; }

    float m0,m1,m2,m3,m4,m5,m6,m7,m8,m9,m10,m11,m12,m13,m14;
    float s = 0.f;
    PAIR(0,1,0)  PAIR(0,2,1)  PAIR(0,3,2)  PAIR(0,4,3)  PAIR(0,5,4)
    PAIR(1,2,5)  PAIR(1,3,6)  PAIR(1,4,7)  PAIR(1,5,8)
    PAIR(2,3,9)  PAIR(2,4,10) PAIR(2,5,11)
    PAIR(3,4,12) PAIR(3,5,13)
    PAIR(4,5,14)
#undef PAIR

    // out_k = sqrt(m_k)/max(sqrt(s),eps) = sqrt(m_k * (1/max(s,eps^2)))
    float sc = fmaxf(s, 1e-24f);
    float invs = 1.f / sc;

    float* row = ls + t * 15;  // stride 15 (odd) -> conflict-free LDS writes
    row[0]  = __fsqrt_rn(m0  * invs);
    row[1]  = __fsqrt_rn(m1  * invs);
    row[2]  = __fsqrt_rn(m2  * invs);
    row[3]  = __fsqrt_rn(m3  * invs);
    row[4]  = __fsqrt_rn(m4  * invs);
    row[5]  = __fsqrt_rn(m5  * invs);
    row[6]  = __fsqrt_rn(m6  * invs);
    row[7]  = __fsqrt_rn(m7  * invs);
    row[8]  = __fsqrt_rn(m8  * invs);
    row[9]  = __fsqrt_rn(m9  * invs);
    row[10] = __fsqrt_rn(m10 * invs);
    row[11] = __fsqrt_rn(m11 * invs);
    row[12] = __fsqrt_rn(m12 * invs);
    row[13] = __fsqrt_rn(m13 * invs);
    row[14] = __fsqrt_rn(m14 * invs);

    __syncthreads();

    // Coalesced flush: 3840 contiguous floats per block, 15 full-wave stores
    float* oblk = out + (long long)blockIdx.x * (256 * 15);
    #pragma unroll
    for (int i = 0; i < 15; ++i) {
        int idx = i * 256 + t;
        oblk[idx] = ls[idx];
    }
}

extern "C" void kernel_launch(void* const* d_in, const int* in_sizes, int n_in,
                              void* d_out, int out_size, void* d_ws, size_t ws_size,
                              hipStream_t stream) {
    const float* x    = (const float*)d_in[0];
    const float* pphi = (const float*)d_in[1];
    const float* pth  = (const float*)d_in[2];
    const float* ink  = (const float*)d_in[3];
    const float* inb  = (const float*)d_in[4];
    float* out = (float*)d_out;

    bqnn_kernel<<<BATCH / 256, 256, 0, stream>>>(x, pphi, pth, ink, inb, out);
}